// Round 6
// baseline (53.308 us; speedup 1.0000x reference)
//
#include <hip/hip_runtime.h>
#include <hip/hip_bf16.h>
#include <stdint.h>

// ---------- types ----------
typedef __attribute__((ext_vector_type(8))) short short8;     // 8 bf16 (4 VGPRs) MFMA A/B frag
typedef __attribute__((ext_vector_type(4))) float f32x4;      // MFMA C/D frag
typedef __attribute__((ext_vector_type(4))) unsigned short us4;

static __device__ __forceinline__ unsigned short f2bf(float f) {
    union { float f; uint32_t u; } v; v.f = f;
    uint32_t u = v.u;
    uint32_t r = u + 0x7FFFu + ((u >> 16) & 1u);   // round-to-nearest-even
    return (unsigned short)(r >> 16);
}
static __device__ __forceinline__ float bf2f(unsigned short h) {
    union { uint32_t u; float f; } v; v.u = ((uint32_t)h) << 16;
    return v.f;
}

static __device__ __forceinline__ short8 cvt8(float4 a, float4 b) {
    short8 r;
    r[0] = (short)f2bf(a.x); r[1] = (short)f2bf(a.y);
    r[2] = (short)f2bf(a.z); r[3] = (short)f2bf(a.w);
    r[4] = (short)f2bf(b.x); r[5] = (short)f2bf(b.y);
    r[6] = (short)f2bf(b.z); r[7] = (short)f2bf(b.w);
    return r;
}

// ---------- kernel 0: convert W1 / W2 / W3 f32 -> bf16 ----------
__global__ __launch_bounds__(256) void convert_w(const float* __restrict__ w1,
                                                 const float* __restrict__ w2,
                                                 const float* __restrict__ w3,
                                                 unsigned short* __restrict__ o1,
                                                 unsigned short* __restrict__ o2,
                                                 unsigned short* __restrict__ o3) {
    int b = blockIdx.x;
    const float* src; unsigned short* dst; int idx;
    if (b < 1024)      { src = w1; dst = o1; idx = b * 256 + threadIdx.x; }
    else if (b < 1040) { src = w2; dst = o2; idx = (b - 1024) * 256 + threadIdx.x; }
    else               { src = w3; dst = o3; idx = (b - 1040) * 256 + threadIdx.x; }
    float4 v = ((const float4*)src)[idx];
    us4 r = { f2bf(v.x), f2bf(v.y), f2bf(v.z), f2bf(v.w) };
    *(us4*)&dst[(size_t)idx * 4] = r;
}

// ---------- kernel 1: cb[row] = sum_n (x@W2^T + b2)*(x@W3^T + b3), + x -> bf16 ----------
__global__ __launch_bounds__(256) void cb_kernel(
    const float* __restrict__ x,            // [8192][1024]
    const unsigned short* __restrict__ w2b, // [16][1024] bf16
    const unsigned short* __restrict__ w3b, // [16][1024] bf16
    const float* __restrict__ b2,           // [16]
    const float* __restrict__ b3,           // [16]
    unsigned short* __restrict__ xb,        // out: [8192][1024] bf16
    float* __restrict__ cbo)                // out: [8192]
{
    __shared__ float red[4][2][16][16];     // [wave][B/C][row][n] = 8 KB

    const int t = threadIdx.x;
    const int wave = t >> 6, lane = t & 63;
    const int r0 = blockIdx.x * 16;
    const int rrow = lane & 15;
    const int klane = (lane >> 4) * 8;
    const size_t xrow = (size_t)(r0 + rrow) * 1024;
    const int k0 = wave * 256;

    f32x4 accB = {0.f, 0.f, 0.f, 0.f};
    f32x4 accC = {0.f, 0.f, 0.f, 0.f};

#pragma unroll
    for (int ks = 0; ks < 256; ks += 32) {
        const int k = k0 + ks + klane;
        float4 xa = *(const float4*)&x[xrow + k];
        float4 xc = *(const float4*)&x[xrow + k + 4];
        short8 af = cvt8(xa, xc);
        *(short8*)&xb[xrow + k] = af;
        short8 w2f = *(const short8*)&w2b[(size_t)rrow * 1024 + k];
        short8 w3f = *(const short8*)&w3b[(size_t)rrow * 1024 + k];
        accB = __builtin_amdgcn_mfma_f32_16x16x32_bf16(af, w2f, accB, 0, 0, 0);
        accC = __builtin_amdgcn_mfma_f32_16x16x32_bf16(af, w3f, accC, 0, 0, 0);
    }

#pragma unroll
    for (int j = 0; j < 4; ++j) {
        red[wave][0][(lane >> 4) * 4 + j][lane & 15] = accB[j];
        red[wave][1][(lane >> 4) * 4 + j][lane & 15] = accC[j];
    }
    __syncthreads();

    if (wave == 0) {
        const int n = lane & 15;
        const float b2v = b2[n], b3v = b3[n];
        float prod[4];
#pragma unroll
        for (int j = 0; j < 4; ++j) {
            const int row = (lane >> 4) * 4 + j;
            float Bv = red[0][0][row][n] + red[1][0][row][n]
                     + red[2][0][row][n] + red[3][0][row][n] + b2v;
            float Cv = red[0][1][row][n] + red[1][1][row][n]
                     + red[2][1][row][n] + red[3][1][row][n] + b3v;
            prod[j] = Bv * Cv;
        }
#pragma unroll
        for (int off = 1; off < 16; off <<= 1)
#pragma unroll
            for (int j = 0; j < 4; ++j)
                prod[j] += __shfl_xor(prod[j], off, 64);
        if ((lane & 15) == 0) {
#pragma unroll
            for (int j = 0; j < 4; ++j)
                cbo[r0 + (lane >> 4) * 4 + j] = prod[j];
        }
    }
}

// ---------- kernel 2: delta GEMM + fused epilogue ----------
// BM=256 x BN=128, BK=64, 512 threads (8 waves 2Mx4N, per-wave 128x32).
// Double-buffered LDS (96 KB), XOR-swizzle, XCD remap (per-XCD working set =
// 2MB A-slice + 2MB w1b = one 4MB L2), counted vmcnt(6), 2-phase compute with
// setprio'd MFMA clusters (T3/T4/T5).
__global__ __launch_bounds__(512, 2) void gemm_kernel(
    const unsigned short* __restrict__ xb,   // [8192][1024] bf16
    const unsigned short* __restrict__ w1b,  // [1024][1024] bf16 (N x K)
    const float* __restrict__ b1,            // [1024]
    const float* __restrict__ cb,            // [8192]
    float* __restrict__ y)                   // [8192][1024] f32
{
    __shared__ unsigned short As[2][256 * 64];   // 32 KB each
    __shared__ unsigned short Bs[2][128 * 64];   // 16 KB each

    // XCD remap: grid 256 = 8 XCD * 32. XCD k gets row-blocks [4k,4k+4) x all
    // 8 col-blocks -> per-XCD: 1024 A-rows (2MB bf16) + full w1b (2MB) in L2.
    const int wg = blockIdx.x;
    const int nid = (wg & 7) * 32 + (wg >> 3);
    const int row0 = (nid >> 3) * 256;
    const int col0 = (nid & 7) * 128;

    const int t = threadIdx.x;
    const int wid = t >> 6, lane = t & 63;
    const int wm = wid >> 2, wn = wid & 3;       // 2 x 4 wave grid

    const int trow = t >> 3;                     // 0..63 (staging row group)
    const int tslot = t & 7;                     // 16B slot

    f32x4 acc[8][2];
#pragma unroll
    for (int m = 0; m < 8; ++m)
#pragma unroll
        for (int n = 0; n < 2; ++n)
            acc[m][n] = (f32x4){0.f, 0.f, 0.f, 0.f};

    // 6 global_load_lds per thread per K-tile: 4x A (256 rows) + 2x B (128).
    auto STAGE = [&](int b, int kt) {
#pragma unroll
        for (int p = 0; p < 4; ++p) {
            const int r = trow + p * 64;                 // 0..255
            const int gc = kt + ((tslot ^ (r & 7)) << 3);
            const unsigned short* ga = &xb[(size_t)(row0 + r) * 1024 + gc];
            __builtin_amdgcn_global_load_lds(
                (const __attribute__((address_space(1))) void*)ga,
                (__attribute__((address_space(3))) void*)&As[b][r * 64 + tslot * 8], 16, 0, 0);
        }
#pragma unroll
        for (int p = 0; p < 2; ++p) {
            const int r = trow + p * 64;                 // 0..127
            const int gc = kt + ((tslot ^ (r & 7)) << 3);
            const unsigned short* gb = &w1b[(size_t)(col0 + r) * 1024 + gc];
            __builtin_amdgcn_global_load_lds(
                (const __attribute__((address_space(1))) void*)gb,
                (__attribute__((address_space(3))) void*)&Bs[b][r * 64 + tslot * 8], 16, 0, 0);
        }
    };

    STAGE(0, 0);

    const int ro = lane & 15;
    const int sh = lane >> 4;                    // 0..3

    for (int tk = 0; tk < 16; ++tk) {
        const int cur = tk & 1;
        if (tk < 15) {
            STAGE(cur ^ 1, (tk + 1) * 64);       // 6 new loads in flight
            asm volatile("s_waitcnt vmcnt(6)" ::: "memory");  // cur's 6 landed
        } else {
            asm volatile("s_waitcnt vmcnt(0)" ::: "memory");
        }
        __builtin_amdgcn_s_barrier();            // all waves' cur data in LDS
        __builtin_amdgcn_sched_barrier(0);

        // ---- phase 0: B-frags + A-frags m0..3, MFMA m0..3 ----
        short8 bf[2][2], af[2][4];
#pragma unroll
        for (int ks = 0; ks < 2; ++ks) {
            const int s = ((ks * 4 + sh) ^ (ro & 7)) << 3;
#pragma unroll
            for (int n = 0; n < 2; ++n)
                bf[ks][n] = *(const short8*)&Bs[cur][(wn * 32 + n * 16 + ro) * 64 + s];
#pragma unroll
            for (int m = 0; m < 4; ++m)
                af[ks][m] = *(const short8*)&As[cur][(wm * 128 + m * 16 + ro) * 64 + s];
        }
        asm volatile("s_waitcnt lgkmcnt(0)" ::: "memory");
        __builtin_amdgcn_sched_barrier(0);
        __builtin_amdgcn_s_setprio(1);
#pragma unroll
        for (int ks = 0; ks < 2; ++ks)
#pragma unroll
            for (int m = 0; m < 4; ++m)
#pragma unroll
                for (int n = 0; n < 2; ++n)
                    acc[m][n] = __builtin_amdgcn_mfma_f32_16x16x32_bf16(af[ks][m], bf[ks][n], acc[m][n], 0, 0, 0);
        __builtin_amdgcn_s_setprio(0);
        __builtin_amdgcn_s_barrier();
        __builtin_amdgcn_sched_barrier(0);

        // ---- phase 1: A-frags m4..7, MFMA m4..7 ----
#pragma unroll
        for (int ks = 0; ks < 2; ++ks) {
            const int s = ((ks * 4 + sh) ^ (ro & 7)) << 3;
#pragma unroll
            for (int m = 0; m < 4; ++m)
                af[ks][m] = *(const short8*)&As[cur][(wm * 128 + (m + 4) * 16 + ro) * 64 + s];
        }
        asm volatile("s_waitcnt lgkmcnt(0)" ::: "memory");
        __builtin_amdgcn_sched_barrier(0);
        __builtin_amdgcn_s_setprio(1);
#pragma unroll
        for (int ks = 0; ks < 2; ++ks)
#pragma unroll
            for (int m = 0; m < 4; ++m)
#pragma unroll
                for (int n = 0; n < 2; ++n)
                    acc[m + 4][n] = __builtin_amdgcn_mfma_f32_16x16x32_bf16(af[ks][m], bf[ks][n], acc[m + 4][n], 0, 0, 0);
        __builtin_amdgcn_s_setprio(0);
        // end-of-tile: all reads of cur done (lgkmcnt(0) above) before any
        // wave's next-iter STAGE overwrites cur.
        __builtin_amdgcn_s_barrier();
        __builtin_amdgcn_sched_barrier(0);
    }

    // epilogue: C/D layout col=lane&15, row=(lane>>4)*4+j
#pragma unroll
    for (int m = 0; m < 8; ++m) {
        const int grow_base = row0 + wm * 128 + m * 16 + (lane >> 4) * 4;
#pragma unroll
        for (int n = 0; n < 2; ++n) {
            const int gcol = col0 + wn * 32 + n * 16 + (lane & 15);
            const float bv = b1[gcol];
#pragma unroll
            for (int j = 0; j < 4; ++j) {
                const int grow = grow_base + j;
                const float v = acc[m][n][j] + bv;
                const float sp = (v > 15.f) ? v : __logf(1.f + __expf(v));
                const size_t off = (size_t)grow * 1024 + gcol;
                y[off] = bf2f(xb[off]) * sp * cb[grow];
            }
        }
    }
}

extern "C" void kernel_launch(void* const* d_in, const int* in_sizes, int n_in,
                              void* d_out, int out_size, void* d_ws, size_t ws_size,
                              hipStream_t stream) {
    const float* x  = (const float*)d_in[0];
    const float* W1 = (const float*)d_in[1];
    const float* b1 = (const float*)d_in[2];
    const float* W2 = (const float*)d_in[3];
    const float* b2 = (const float*)d_in[4];
    const float* W3 = (const float*)d_in[5];
    const float* b3 = (const float*)d_in[6];
    // d_in[7] (A) is a dead parameter in the reference (multiplied by zeros)

    float* y = (float*)d_out;

    unsigned short* xb  = (unsigned short*)d_ws;                 // 16 MB
    unsigned short* w1b = xb + (size_t)8192 * 1024;              // 2 MB
    unsigned short* w2b = w1b + (size_t)1024 * 1024;             // 32 KB
    unsigned short* w3b = w2b + (size_t)16 * 1024;               // 32 KB
    float* cbuf = (float*)(w3b + (size_t)16 * 1024);             // 32 KB

    convert_w<<<1056, 256, 0, stream>>>(W1, W2, W3, w1b, w2b, w3b);
    cb_kernel<<<512, 256, 0, stream>>>(x, w2b, w3b, b2, b3, xb, cbuf);
    gemm_kernel<<<256, 512, 0, stream>>>(xb, w1b, b1, cbuf, y);
}

// Round 7
// 46.096 us; speedup vs baseline: 1.1565x; 1.1565x over previous
//
#include <hip/hip_runtime.h>
#include <hip/hip_bf16.h>
#include <stdint.h>

// ---------- types ----------
typedef __attribute__((ext_vector_type(8))) short short8;     // 8 bf16 (4 VGPRs) MFMA A/B frag
typedef __attribute__((ext_vector_type(4))) float f32x4;      // MFMA C/D frag
typedef __attribute__((ext_vector_type(4))) unsigned short us4;

static __device__ __forceinline__ unsigned short f2bf(float f) {
    // native RNE conversion -> compiler emits v_cvt_pk_bf16_f32 pairs
    __hip_bfloat16 h = __float2bfloat16(f);
    union { __hip_bfloat16 h; unsigned short u; } v; v.h = h;
    return v.u;
}
static __device__ __forceinline__ float bf2f(unsigned short h) {
    union { uint32_t u; float f; } v; v.u = ((uint32_t)h) << 16;
    return v.f;
}

static __device__ __forceinline__ short8 cvt8(float4 a, float4 b) {
    short8 r;
    r[0] = (short)f2bf(a.x); r[1] = (short)f2bf(a.y);
    r[2] = (short)f2bf(a.z); r[3] = (short)f2bf(a.w);
    r[4] = (short)f2bf(b.x); r[5] = (short)f2bf(b.y);
    r[6] = (short)f2bf(b.z); r[7] = (short)f2bf(b.w);
    return r;
}

// ---------- kernel 1 (fused): cb + x->bf16 + W1->bf16 ----------
// blocks 0..511 : cb[row] = sum_n (x@W2^T + b2)*(x@W3^T + b3), xb = bf16(x)
//                 (W2/W3 converted in-register from f32; L2-resident, 128 KB)
// blocks 512..575: W1 (1M f32) -> w1b bf16, 16384 elems/block
__global__ __launch_bounds__(256) void cb_fused(
    const float* __restrict__ x,            // [8192][1024]
    const float* __restrict__ W1,           // [1024][1024]
    const float* __restrict__ W2,           // [16][1024]
    const float* __restrict__ b2,           // [16]
    const float* __restrict__ W3,           // [16][1024]
    const float* __restrict__ b3,           // [16]
    unsigned short* __restrict__ xb,        // out: [8192][1024] bf16
    unsigned short* __restrict__ w1b,       // out: [1024][1024] bf16
    float* __restrict__ cbo)                // out: [8192]
{
    const int bid = blockIdx.x;
    const int t = threadIdx.x;

    if (bid >= 512) {
        // ---- W1 conversion: 64 blocks x 4096 float4 ----
        const int base = (bid - 512) * 4096 + t;     // float4 index
        const float4* w4 = (const float4*)W1;
#pragma unroll
        for (int i = 0; i < 16; ++i) {
            float4 v = w4[base + i * 256];
            us4 r = { f2bf(v.x), f2bf(v.y), f2bf(v.z), f2bf(v.w) };
            *(us4*)&w1b[(size_t)(base + i * 256) * 4] = r;
        }
        return;
    }

    __shared__ float red[4][2][16][16];     // [wave][B/C][row][n] = 8 KB

    const int wave = t >> 6, lane = t & 63;
    const int r0 = bid * 16;
    const int rrow = lane & 15;
    const int klane = (lane >> 4) * 8;
    const size_t xrow = (size_t)(r0 + rrow) * 1024;
    const int k0 = wave * 256;

    f32x4 accB = {0.f, 0.f, 0.f, 0.f};
    f32x4 accC = {0.f, 0.f, 0.f, 0.f};

#pragma unroll
    for (int ks = 0; ks < 256; ks += 32) {
        const int k = k0 + ks + klane;
        float4 xa = *(const float4*)&x[xrow + k];
        float4 xc = *(const float4*)&x[xrow + k + 4];
        short8 af = cvt8(xa, xc);
        *(short8*)&xb[xrow + k] = af;
        // W2/W3 row rrow, in-register f32 -> bf16 (same RNE bits as before)
        float4 w2a = *(const float4*)&W2[(size_t)rrow * 1024 + k];
        float4 w2c = *(const float4*)&W2[(size_t)rrow * 1024 + k + 4];
        float4 w3a = *(const float4*)&W3[(size_t)rrow * 1024 + k];
        float4 w3c = *(const float4*)&W3[(size_t)rrow * 1024 + k + 4];
        short8 w2f = cvt8(w2a, w2c);
        short8 w3f = cvt8(w3a, w3c);
        accB = __builtin_amdgcn_mfma_f32_16x16x32_bf16(af, w2f, accB, 0, 0, 0);
        accC = __builtin_amdgcn_mfma_f32_16x16x32_bf16(af, w3f, accC, 0, 0, 0);
    }

#pragma unroll
    for (int j = 0; j < 4; ++j) {
        red[wave][0][(lane >> 4) * 4 + j][lane & 15] = accB[j];
        red[wave][1][(lane >> 4) * 4 + j][lane & 15] = accC[j];
    }
    __syncthreads();

    if (wave == 0) {
        const int n = lane & 15;
        const float b2v = b2[n], b3v = b3[n];
        float prod[4];
#pragma unroll
        for (int j = 0; j < 4; ++j) {
            const int row = (lane >> 4) * 4 + j;
            float Bv = red[0][0][row][n] + red[1][0][row][n]
                     + red[2][0][row][n] + red[3][0][row][n] + b2v;
            float Cv = red[0][1][row][n] + red[1][1][row][n]
                     + red[2][1][row][n] + red[3][1][row][n] + b3v;
            prod[j] = Bv * Cv;
        }
#pragma unroll
        for (int off = 1; off < 16; off <<= 1)
#pragma unroll
            for (int j = 0; j < 4; ++j)
                prod[j] += __shfl_xor(prod[j], off, 64);
        if ((lane & 15) == 0) {
#pragma unroll
            for (int j = 0; j < 4; ++j)
                cbo[r0 + (lane >> 4) * 4 + j] = prod[j];
        }
    }
}

// ---------- kernel 2: delta GEMM + fused epilogue (round-5 structure) ----------
// 128x128 tile, BK=64, double-buffered LDS, XOR-swizzle, XCD row-chunk remap,
// counted vmcnt(8) pipeline (T4) + setprio around MFMA (T5). 2 blocks/CU.
__global__ __launch_bounds__(256, 2) void gemm_kernel(
    const unsigned short* __restrict__ xb,   // [8192][1024] bf16
    const unsigned short* __restrict__ w1b,  // [1024][1024] bf16 (N x K)
    const float* __restrict__ b1,            // [1024]
    const float* __restrict__ cb,            // [8192]
    float* __restrict__ y)                   // [8192][1024] f32
{
    __shared__ unsigned short As[2][128 * 64];
    __shared__ unsigned short Bs[2][128 * 64];

    // XCD row-chunk remap (bijective, 512 = 8 XCD * 64)
    const int wg = blockIdx.x;
    const int nid = (wg & 7) * 64 + (wg >> 3);
    const int row0 = (nid >> 3) * 128;
    const int col0 = (nid & 7) * 128;

    const int t = threadIdx.x;
    const int wid = t >> 6, lane = t & 63;
    const int wm = wid >> 1, wn = wid & 1;

    const int lrow = lane >> 3;              // 0..7 (row within 8-row group)
    const int gslot = (lane & 7) ^ lrow;     // pre-swizzled 16B slot in global

    f32x4 acc[4][4];
#pragma unroll
    for (int m = 0; m < 4; ++m)
#pragma unroll
        for (int n = 0; n < 4; ++n)
            acc[m][n] = (f32x4){0.f, 0.f, 0.f, 0.f};

    // Each wave issues exactly 8 global_load_lds per STAGE (4 rounds x A,B).
    auto STAGE = [&](int b, int kt) {
#pragma unroll
        for (int p = 0; p < 4; ++p) {
            const int grp = p * 4 + wid;            // 0..15 -> 8 rows each
            const int row = grp * 8 + lrow;         // 0..127
            const int gc = kt + gslot * 8;          // swizzled source column
            const unsigned short* ga = &xb[(size_t)(row0 + row) * 1024 + gc];
            const unsigned short* gb = &w1b[(size_t)(col0 + row) * 1024 + gc];
            __builtin_amdgcn_global_load_lds(
                (const __attribute__((address_space(1))) void*)ga,
                (__attribute__((address_space(3))) void*)&As[b][grp * 512 + lane * 8], 16, 0, 0);
            __builtin_amdgcn_global_load_lds(
                (const __attribute__((address_space(1))) void*)gb,
                (__attribute__((address_space(3))) void*)&Bs[b][grp * 512 + lane * 8], 16, 0, 0);
        }
    };

    STAGE(0, 0);
    asm volatile("s_waitcnt vmcnt(0)" ::: "memory");
    __builtin_amdgcn_s_barrier();
    __builtin_amdgcn_sched_barrier(0);

    const int ro = lane & 15;
    const int sh = lane >> 4;                // 0..3

    for (int tk = 0; tk < 16; ++tk) {
        const int cur = tk & 1;
        if (tk < 15) {
            STAGE(cur ^ 1, (tk + 1) * 64);           // 8 new loads in flight
            asm volatile("s_waitcnt vmcnt(8)" ::: "memory");
        } else {
            asm volatile("s_waitcnt vmcnt(0)" ::: "memory");
        }
        __builtin_amdgcn_s_barrier();      // all waves' cur-loads have landed
        __builtin_amdgcn_sched_barrier(0); // no ds_read hoisting above barrier

        short8 af[2][4], bfr[2][4];
#pragma unroll
        for (int ks = 0; ks < 2; ++ks) {
            const int s = ks * 4 + sh;       // 16B slot within 128B row
#pragma unroll
            for (int m = 0; m < 4; ++m) {
                const int ar = wm * 64 + m * 16 + ro;
                af[ks][m]  = *(const short8*)&As[cur][ar * 64 + ((s ^ (ro & 7)) << 3)];
                const int br = wn * 64 + m * 16 + ro;
                bfr[ks][m] = *(const short8*)&Bs[cur][br * 64 + ((s ^ (ro & 7)) << 3)];
            }
        }
        __builtin_amdgcn_s_setprio(1);
#pragma unroll
        for (int ks = 0; ks < 2; ++ks)
#pragma unroll
            for (int m = 0; m < 4; ++m)
#pragma unroll
                for (int n = 0; n < 4; ++n)
                    acc[m][n] = __builtin_amdgcn_mfma_f32_16x16x32_bf16(af[ks][m], bfr[ks][n], acc[m][n], 0, 0, 0);
        __builtin_amdgcn_s_setprio(0);

        // WAR guard: our ds_reads of buf cur must complete before next-iter
        // STAGE overwrites it.
        asm volatile("s_waitcnt lgkmcnt(0)" ::: "memory");
        __builtin_amdgcn_s_barrier();
        __builtin_amdgcn_sched_barrier(0);
    }

    // epilogue: C/D layout col=lane&15, row=(lane>>4)*4+j
#pragma unroll
    for (int m = 0; m < 4; ++m) {
        const int grow_base = row0 + wm * 64 + m * 16 + (lane >> 4) * 4;
#pragma unroll
        for (int n = 0; n < 4; ++n) {
            const int gcol = col0 + wn * 64 + n * 16 + (lane & 15);
            const float bv = b1[gcol];
#pragma unroll
            for (int j = 0; j < 4; ++j) {
                const int grow = grow_base + j;
                const float v = acc[m][n][j] + bv;
                const float sp = (v > 15.f) ? v : __logf(1.f + __expf(v));
                const size_t off = (size_t)grow * 1024 + gcol;
                y[off] = bf2f(xb[off]) * sp * cb[grow];
            }
        }
    }
}

extern "C" void kernel_launch(void* const* d_in, const int* in_sizes, int n_in,
                              void* d_out, int out_size, void* d_ws, size_t ws_size,
                              hipStream_t stream) {
    const float* x  = (const float*)d_in[0];
    const float* W1 = (const float*)d_in[1];
    const float* b1 = (const float*)d_in[2];
    const float* W2 = (const float*)d_in[3];
    const float* b2 = (const float*)d_in[4];
    const float* W3 = (const float*)d_in[5];
    const float* b3 = (const float*)d_in[6];
    // d_in[7] (A) is a dead parameter in the reference (multiplied by zeros)

    float* y = (float*)d_out;

    unsigned short* xb  = (unsigned short*)d_ws;                 // 16 MB
    unsigned short* w1b = xb + (size_t)8192 * 1024;              // 2 MB
    float* cbuf = (float*)(w1b + (size_t)1024 * 1024);           // 32 KB

    cb_fused<<<576, 256, 0, stream>>>(x, W1, W2, b2, W3, b3, xb, w1b, cbuf);
    gemm_kernel<<<512, 256, 0, stream>>>(xb, w1b, b1, cbuf, y);
}